// Round 1
// baseline (22.253 us; speedup 1.0000x reference)
//
#include <hip/hip_runtime.h>
#include <math.h>

namespace {

constexpr int BATCH = 16;
constexpr int Hh = 96;
constexpr int Ww = 96;
constexpr int NP = Hh * Ww;      // 9216
constexpr int NHYP = 128;

__device__ inline double waveSumD(double v) {
#pragma unroll
  for (int o = 32; o >= 1; o >>= 1) v += __shfl_xor(v, o, 64);
  return v;
}
__device__ inline int waveSumI(int v) {
#pragma unroll
  for (int o = 32; o >= 1; o >>= 1) v += __shfl_xor(v, o, 64);
  return v;
}

// block of exactly 128 threads (2 waves); sh must be double[2]
__device__ inline double blockSum128(double v, double* sh) {
  v = waveSumD(v);
  int wv = threadIdx.x >> 6;
  __syncthreads();                       // protect prior use of sh
  if ((threadIdx.x & 63) == 0) sh[wv] = v;
  __syncthreads();
  return sh[0] + sh[1];
}

// Kernel A: per (b,n) solve 2x2, per-b stats, outlier replace, flags.
__global__ __launch_bounds__(128)
void hyp_kernel(const float* __restrict__ uv, const int* __restrict__ pair,
                double* __restrict__ Yp, int* __restrict__ flags) {
  __shared__ double sh[2];
  int b = blockIdx.x;
  int n = threadIdx.x;
  int i0 = pair[(b * NHYP + n) * 2 + 0];
  int i1 = pair[(b * NHYP + n) * 2 + 1];
  const float* uvb = uv + (size_t)b * 2 * NP;
  double u0 = uvb[i0], v0 = uvb[NP + i0];
  double u1 = uvb[i1], v1 = uvb[NP + i1];
  double y0 = (double)(i0 / Ww), x0 = (double)(i0 % Ww);
  double y1 = (double)(i1 / Ww), x1 = (double)(i1 % Ww);
  // A = [[u0, -u1],[v0, -v1]], Bvec = [y1-y0, x1-x0], s = first comp of A^-1 B
  double det = u1 * v0 - u0 * v1;
  double s = (u1 * (x1 - x0) - v1 * (y1 - y0)) / det;
  double Yy = s * u0 + y0;
  double Yx = s * v0 + x0;

  double my = blockSum128(Yy, sh) * (1.0 / NHYP);
  double mx = blockSum128(Yx, sh) * (1.0 / NHYP);
  double dy = Yy - my, dx = Yx - mx;
  double vy = blockSum128(dy * dy, sh) * (1.0 / (NHYP - 1));
  double vx = blockSum128(dx * dx, sh) * (1.0 / (NHYP - 1));
  double sdy = sqrt(vy), sdx = sqrt(vx);
  // one-sided z-score, NaN (0/0) compares false like the reference
  bool outl = (dy / sdy > 2.0) || (dx / sdx > 2.0);
  double py = outl ? my : Yy;
  double px = outl ? mx : Yx;
  int bn = b * NHYP + n;
  Yp[bn * 2 + 0] = py;
  Yp[bn * 2 + 1] = px;
  // h_in_mask==1  <=>  trunc(Yp) hits a lattice point  <=>  Yp in (-1,96)^2
  float fy = (float)py, fx = (float)px;
  int f = 0;
  if (fy > -1.0f && fy < 96.0f && fx > -1.0f && fx < 96.0f) f |= 1;
  if (isnan(py) || isnan(px)) f |= 2;
  flags[bn] = f;
}

// Kernel B: vote count per (b,n). Normalization dropped (sign-preserving).
__global__ __launch_bounds__(256)
void vote_kernel(const float* __restrict__ uv, const double* __restrict__ Yp,
                 int* __restrict__ counts) {
  int bn = blockIdx.x;
  int b = bn >> 7;
  const float* uvb = uv + (size_t)b * 2 * NP;
  float yy = (float)Yp[bn * 2 + 0];
  float yx = (float)Yp[bn * 2 + 1];
  int cnt = 0;
  for (int p = threadIdx.x; p < NP; p += 256) {
    int y = p / Ww;
    int x = p - y * Ww;
    float u = uvb[p];
    float v = uvb[NP + p];
    float dot = (yy - (float)y) * u + (yx - (float)x) * v;
    cnt += (dot > 0.0f) ? 1 : 0;     // NaN -> false, matches reference
  }
  cnt = waveSumI(cnt);
  __shared__ int sh[4];
  int wv = threadIdx.x >> 6;
  if ((threadIdx.x & 63) == 0) sh[wv] = cnt;
  __syncthreads();
  if (threadIdx.x == 0) counts[bn] = sh[0] + sh[1] + sh[2] + sh[3];
}

// Kernel C: weights, normalize, NaN zeroing, weighted mean, reversed output.
__global__ __launch_bounds__(128)
void final_kernel(const double* __restrict__ Yp, const int* __restrict__ flags,
                  const int* __restrict__ counts, float* __restrict__ out) {
  __shared__ double sh[2];
  int b = blockIdx.x;
  int n = threadIdx.x;
  int bn = b * NHYP + n;
  int f = flags[bn];
  double w = (double)counts[bn];
  if (f & 1) w *= 10.0;
  double wsum = blockSum128(w, sh);
  double wn = w / wsum;
  double py = Yp[bn * 2 + 0], px = Yp[bn * 2 + 1];
  if (f & 2) { wn = 0.0; py = 0.0; px = 0.0; }   // is_nan: w->0, Yp->0
  double oy = blockSum128(py * wn, sh);
  double ox = blockSum128(px * wn, sh);
  if (n == 0) {
    out[b * 2 + 0] = (float)ox;    // weighted_mean[:, ::-1]
    out[b * 2 + 1] = (float)oy;
  }
}

}  // namespace

extern "C" void kernel_launch(void* const* d_in, const int* in_sizes, int n_in,
                              void* d_out, int out_size, void* d_ws, size_t ws_size,
                              hipStream_t stream) {
  const float* uv = (const float*)d_in[0];      // (16,2,96,96) f32
  // d_in[1] = mask, unused (all ones in setup, never read by reference math)
  const int* pair = (const int*)d_in[2];        // (16,128,2) i32
  float* out = (float*)d_out;                   // (16,2) f32

  char* ws = (char*)d_ws;
  double* Yp   = (double*)ws;                   // 16*128*2*8  = 32768 B
  int* flags   = (int*)(ws + 32768);            // 16*128*4    =  8192 B
  int* counts  = (int*)(ws + 32768 + 8192);     // 16*128*4    =  8192 B

  hyp_kernel<<<BATCH, NHYP, 0, stream>>>(uv, pair, Yp, flags);
  vote_kernel<<<BATCH * NHYP, 256, 0, stream>>>(uv, Yp, counts);
  final_kernel<<<BATCH, NHYP, 0, stream>>>(Yp, flags, counts, out);
}